// Round 6
// baseline (79.303 us; speedup 1.0000x reference)
//
#include <hip/hip_runtime.h>

// RetinaNetFocalLoss on MI355X (gfx950).
// Inputs: clas_preds (16,49152,80) f32, bbox_preds (16,49152,4) f32,
//         bbox_tgts (16,64,4) f32 tlbr, clas_tgts (16,64) i32, anchors (49152,4) f32 cthw.
// Output: single f32 scalar.
//
// v6: focal = pure unmasked stream (no codes, no LDS, no sync).
//     match = IoU/huber + hot-class correction + excluded-anchor subtraction
//             (ballot-compacted, 20 threads per excluded anchor).
//     finalize = coalesced load of all partials -> LDS -> per-wave reduce.

#define A_CNT 49152
#define T_CNT 64
#define C_CNT 80
#define ABLK  256
#define NBLK  (A_CNT / ABLK)   // 192
#define B_CNT 16
#define NSLOT (B_CNT * NBLK)   // 3072

#define LN2   0.6931471806f
#define RLN2  1.44269504f

typedef float f32x4 __attribute__((ext_vector_type(4)));

// sigma(x)^2 * log2(1+e^x)  — caller scales by 0.25*ln2
__device__ __forceinline__ float focal_l2(float x) {
    float e  = __builtin_amdgcn_exp2f(x * RLN2);         // e^x
    float t  = 1.0f + e;
    float ps = e * __builtin_amdgcn_rcpf(t);             // sigmoid(x)
    float L  = __builtin_amdgcn_logf(t);                 // log2(1+e^x)
    return ps * ps * L;
}

// ---------- Kernel 1: pure focal streamer (no dependencies) ----------
__global__ __launch_bounds__(ABLK) void rnfl_focal(
    const float* __restrict__ clas_preds,
    float* __restrict__ fl_part)
{
    const int tid = threadIdx.x;
    const int b   = blockIdx.y;
    const int bx  = blockIdx.x;

    const f32x4* cp4 = reinterpret_cast<const f32x4*>(clas_preds)
                     + ((size_t)b * A_CNT + bx * ABLK) * (C_CNT / 4);

    float acc0 = 0.0f, acc1 = 0.0f;
#pragma unroll
    for (int k = 0; k < 20; k += 2) {
        f32x4 v0 = __builtin_nontemporal_load(cp4 + (k       * ABLK + tid));
        f32x4 v1 = __builtin_nontemporal_load(cp4 + ((k + 1) * ABLK + tid));
        acc0 += (focal_l2(v0.x) + focal_l2(v0.y)) + (focal_l2(v0.z) + focal_l2(v0.w));
        acc1 += (focal_l2(v1.x) + focal_l2(v1.y)) + (focal_l2(v1.z) + focal_l2(v1.w));
    }
    float fl = (acc0 + acc1) * (0.25f * LN2);

    __shared__ float rfl[4];
#pragma unroll
    for (int off = 32; off > 0; off >>= 1)
        fl += __shfl_down(fl, off);
    const int wave = tid >> 6, lane = tid & 63;
    if (lane == 0) rfl[wave] = fl;
    __syncthreads();
    if (tid == 0)
        fl_part[b * NBLK + bx] = rfl[0] + rfl[1] + rfl[2] + rfl[3];
}

// ---------- Kernel 2: matching + huber + focal corrections ----------
__global__ __launch_bounds__(ABLK) void rnfl_match(
    const float* __restrict__ clas_preds,
    const float* __restrict__ bbox_preds,
    const float* __restrict__ bbox_tgts,
    const int*   __restrict__ clas_tgts,
    const float* __restrict__ anchors,
    float* __restrict__ bb_part,
    float* __restrict__ flc_part,
    float* __restrict__ m_part)
{
    const int tid = threadIdx.x;
    const int b   = blockIdx.y;
    const int a0  = blockIdx.x * ABLK;

    __shared__ float4 tbox[T_CNT];
    __shared__ int    tcl[T_CNT];
    __shared__ int    wcnt[4];
    __shared__ int    excl_idx[ABLK];
    __shared__ float  rv[4][4];

    if (tid < T_CNT) {
        float4 bt = reinterpret_cast<const float4*>(bbox_tgts)[b * T_CNT + tid];
        // tlbr -> cthw -> tlbr (reference roundtrip)
        float cx = (bt.x + bt.z) * 0.5f;
        float cy = (bt.y + bt.w) * 0.5f;
        float sx = bt.z - bt.x;
        float sy = bt.w - bt.y;
        float4 tb;
        tb.x = cx - sx * 0.5f;
        tb.y = cy - sy * 0.5f;
        tb.z = cx + sx * 0.5f;
        tb.w = cy + sy * 0.5f;
        tbox[tid] = tb;
        tcl[tid]  = clas_tgts[b * T_CNT + tid];
    }
    __syncthreads();

    const int a = a0 + tid;
    float4 anc = reinterpret_cast<const float4*>(anchors)[a];
    const float ax1 = anc.x - anc.z * 0.5f;
    const float ay1 = anc.y - anc.w * 0.5f;
    const float ax2 = anc.x + anc.z * 0.5f;
    const float ay2 = anc.y + anc.w * 0.5f;
    const float areaA = anc.z * anc.w;

    float bn = -1.0f, bd = 1.0f;
    int   bj = 0;
#pragma unroll 8
    for (int j = 0; j < T_CNT; ++j) {
        float4 tb = tbox[j];                 // wave-uniform b128 broadcast
        float ix1 = fmaxf(ax1, tb.x);
        float iy1 = fmaxf(ay1, tb.y);
        float ix2 = fminf(ax2, tb.z);
        float iy2 = fminf(ay2, tb.w);
        float w = fmaxf(ix2 - ix1, 0.0f);
        float h = fmaxf(iy2 - iy1, 0.0f);
        float inter = w * h;
        float den = areaA + (tb.z - tb.x) * (tb.w - tb.y) - inter + 1e-8f;
        if (inter * bd > bn * den) { bn = inter; bd = den; bj = j; }  // first-max
    }

    const f32x4* cp4b = reinterpret_cast<const f32x4*>(clas_preds)
                      + ((size_t)b * A_CNT + a0) * (C_CNT / 4);

    float bb   = 0.0f;
    float flc  = 0.0f;   // hot correction (scaled)
    float craw = 0.0f;   // raw excl-anchor focal_l2 sum (scaled later)
    float mloc = 0.0f;
    bool  excl = false;

    if (bn > 0.5f * bd) {                    // iou > MATCH_THR
        mloc = 1.0f;
        int code = tcl[bj] - 1;              // hot class in [0,79]
        float4 tb = tbox[bj];
        float gx = (tb.x + tb.z) * 0.5f;
        float gy = (tb.y + tb.w) * 0.5f;
        float gw = tb.z - tb.x;
        float gh = tb.w - tb.y;
        float4 bp = reinterpret_cast<const float4*>(bbox_preds)[(size_t)b * A_CNT + a];
        float t0 = ((gx - anc.x) / anc.z) * 10.0f;       // / SCALE 0.1
        float t1 = ((gy - anc.y) / anc.w) * 10.0f;
        float t2 = __logf(gw / anc.z + 1e-8f) * 5.0f;    // / SCALE 0.2
        float t3 = __logf(gh / anc.w + 1e-8f) * 5.0f;
        float d, ad;
        d = bp.x - t0; ad = fabsf(d); bb += (ad < 1.0f) ? 0.5f * d * d : ad - 0.5f;
        d = bp.y - t1; ad = fabsf(d); bb += (ad < 1.0f) ? 0.5f * d * d : ad - 0.5f;
        d = bp.z - t2; ad = fabsf(d); bb += (ad < 1.0f) ? 0.5f * d * d : ad - 0.5f;
        d = bp.w - t3; ad = fabsf(d); bb += (ad < 1.0f) ? 0.5f * d * d : ad - 0.5f;

        // hot focal correction, same log2-form as the streamer for tight cancel
        float x  = clas_preds[((size_t)b * A_CNT + a) * C_CNT + code];
        float e  = __builtin_amdgcn_exp2f(x * RLN2);
        float t  = 1.0f + e;
        float inv = __builtin_amdgcn_rcpf(t);
        float ps = e * inv;
        float q  = 1.0f - ps;
        float L  = __builtin_amdgcn_logf(t);
        float sp = LN2 * L;                              // softplus(x)
        flc = 0.75f * q * q * (sp - x) - 0.25f * ps * ps * sp;
    } else {
        excl = (bn >= 0.4f * bd);            // 0.4 <= iou <= 0.5: excluded
    }

    // ---- compact excluded anchors (deterministic ballot order) ----
    const int lane = tid & 63, wave = tid >> 6;
    unsigned long long bm = __ballot(excl);
    if (lane == 0) wcnt[wave] = __popcll(bm);
    __syncthreads();
    int wbase = 0;
#pragma unroll
    for (int w = 0; w < 4; ++w) wbase += (w < wave) ? wcnt[w] : 0;
    const int E = wcnt[0] + wcnt[1] + wcnt[2] + wcnt[3];
    if (excl) {
        int rank = wbase + __popcll(bm & ((1ull << lane) - 1ull));
        excl_idx[rank] = tid;
    }
    __syncthreads();

    // ---- subtract excluded anchors' unmasked focal (20 threads/anchor) ----
    for (int base = 0; base < E; base += 12) {
        int idx  = base + tid / 20;
        int part = tid % 20;
        if (tid < 240 && idx < E) {
            int al = excl_idx[idx];
            f32x4 v = cp4b[(size_t)al * 20 + part];
            craw -= (focal_l2(v.x) + focal_l2(v.y)) + (focal_l2(v.z) + focal_l2(v.w));
        }
    }

    // ---- block reduction of {bb, flc+scaled craw, m} ----
    flc = fmaf(0.25f * LN2, craw, flc);
#pragma unroll
    for (int off = 32; off > 0; off >>= 1) {
        bb   += __shfl_down(bb, off);
        flc  += __shfl_down(flc, off);
        mloc += __shfl_down(mloc, off);
    }
    if (lane == 0) { rv[wave][0] = bb; rv[wave][1] = flc; rv[wave][2] = mloc; }
    __syncthreads();
    if (tid == 0) {
        int slot = b * NBLK + blockIdx.x;
        bb_part[slot]  = rv[0][0] + rv[1][0] + rv[2][0] + rv[3][0];
        flc_part[slot] = rv[0][1] + rv[1][1] + rv[2][1] + rv[3][1];
        m_part[slot]   = rv[0][2] + rv[1][2] + rv[2][2] + rv[3][2];
    }
}

// ---------- Kernel 3: finalize (coalesced -> LDS -> per-wave reduce) ----------
__global__ __launch_bounds__(256) void rnfl_final(
    const float* __restrict__ bb_part,
    const float* __restrict__ fl_part,
    const float* __restrict__ flc_part,
    const float* __restrict__ m_part,
    float* __restrict__ out)
{
    __shared__ float bbL[NSLOT], flL[NSLOT], fcL[NSLOT], mL[NSLOT];  // 48 KB
    __shared__ float wacc[4];
    const int tid = threadIdx.x, lane = tid & 63, wave = tid >> 6;

#pragma unroll
    for (int k = 0; k < NSLOT / 256; ++k) {   // 12 coalesced loads per array
        int s = k * 256 + tid;
        bbL[s] = bb_part[s];
        flL[s] = fl_part[s];
        fcL[s] = flc_part[s];
        mL[s]  = m_part[s];
    }
    __syncthreads();

    float lacc = 0.0f;
    for (int img = wave; img < B_CNT; img += 4) {
        float bb = 0.0f, fl = 0.0f, m = 0.0f;
#pragma unroll
        for (int s = 0; s < 3; ++s) {         // 3*64 = 192 = NBLK
            int i = img * NBLK + s * 64 + lane;
            bb += bbL[i];
            fl += flL[i] + fcL[i];
            m  += mL[i];
        }
#pragma unroll
        for (int off = 32; off > 0; off >>= 1) {
            bb += __shfl_down(bb, off);
            fl += __shfl_down(fl, off);
            m  += __shfl_down(m, off);
        }
        if (lane == 0)
            lacc += bb / fmaxf(m * 4.0f, 1.0f) + fl / fmaxf(m, 1.0f);
    }
    if (lane == 0) wacc[wave] = lacc;
    __syncthreads();
    if (tid == 0)
        out[0] = (wacc[0] + wacc[1] + wacc[2] + wacc[3]) / (float)B_CNT;
}

extern "C" void kernel_launch(void* const* d_in, const int* in_sizes, int n_in,
                              void* d_out, int out_size, void* d_ws, size_t ws_size,
                              hipStream_t stream)
{
    const float* clas_preds = (const float*)d_in[0];
    const float* bbox_preds = (const float*)d_in[1];
    const float* bbox_tgts  = (const float*)d_in[2];
    const int*   clas_tgts  = (const int*)d_in[3];
    const float* anchors    = (const float*)d_in[4];
    float* out = (float*)d_out;

    float* bb_part  = (float*)d_ws;
    float* fl_part  = bb_part  + NSLOT;
    float* flc_part = fl_part  + NSLOT;
    float* m_part   = flc_part + NSLOT;

    dim3 grid(NBLK, B_CNT);
    rnfl_focal<<<grid, ABLK, 0, stream>>>(clas_preds, fl_part);
    rnfl_match<<<grid, ABLK, 0, stream>>>(clas_preds, bbox_preds, bbox_tgts,
                                          clas_tgts, anchors,
                                          bb_part, flc_part, m_part);
    rnfl_final<<<1, 256, 0, stream>>>(bb_part, fl_part, flc_part, m_part, out);
}

// Round 7
// 68.876 us; speedup vs baseline: 1.1514x; 1.1514x over previous
//
#include <hip/hip_runtime.h>

// RetinaNetFocalLoss on MI355X (gfx950).
// Inputs: clas_preds (16,49152,80) f32, bbox_preds (16,49152,4) f32,
//         bbox_tgts (16,64,4) f32 tlbr, clas_tgts (16,64) i32, anchors (49152,4) f32 cthw.
// Output: single f32 scalar.
//
// v7: ONE main dispatch, block-role partitioned (parity-interleaved):
//     even blocks = pure focal stream (memory-bound), odd blocks = matching/
//     huber/corrections (VALU-bound). Roles co-reside on every CU so the
//     match compute hides under the focal memory stream instead of
//     serializing after it. Finalize unchanged.

#define A_CNT 49152
#define T_CNT 64
#define C_CNT 80
#define ABLK  256
#define NBLK  (A_CNT / ABLK)   // 192
#define B_CNT 16
#define NSLOT (B_CNT * NBLK)   // 3072

#define LN2   0.6931471806f
#define RLN2  1.44269504f

typedef float f32x4 __attribute__((ext_vector_type(4)));

// sigma(x)^2 * log2(1+e^x)  — caller scales by 0.25*ln2
__device__ __forceinline__ float focal_l2(float x) {
    float e  = __builtin_amdgcn_exp2f(x * RLN2);         // e^x
    float t  = 1.0f + e;
    float ps = e * __builtin_amdgcn_rcpf(t);             // sigmoid(x)
    float L  = __builtin_amdgcn_logf(t);                 // log2(1+e^x)
    return ps * ps * L;
}

// ---------- Main kernel: role-split focal stream / matching ----------
__global__ __launch_bounds__(ABLK, 4) void rnfl_main(
    const float* __restrict__ clas_preds,
    const float* __restrict__ bbox_preds,
    const float* __restrict__ bbox_tgts,
    const int*   __restrict__ clas_tgts,
    const float* __restrict__ anchors,
    float* __restrict__ bb_part,
    float* __restrict__ fl_part,
    float* __restrict__ flc_part,
    float* __restrict__ m_part)
{
    const int tid  = threadIdx.x;
    const int role = blockIdx.x & 1;
    const int bid2 = blockIdx.x >> 1;          // [0, 3072)
    const int b    = bid2 / NBLK;
    const int bx   = bid2 - b * NBLK;
    const int lane = tid & 63, wave = tid >> 6;

    if (role == 0) {
        // ================= FOCAL STREAM (memory-bound) =================
        const f32x4* cp4 = reinterpret_cast<const f32x4*>(clas_preds)
                         + ((size_t)b * A_CNT + bx * ABLK) * (C_CNT / 4);

        float acc0 = 0.0f, acc1 = 0.0f;
#pragma unroll
        for (int k = 0; k < 20; k += 2) {
            f32x4 v0 = __builtin_nontemporal_load(cp4 + (k       * ABLK + tid));
            f32x4 v1 = __builtin_nontemporal_load(cp4 + ((k + 1) * ABLK + tid));
            acc0 += (focal_l2(v0.x) + focal_l2(v0.y)) + (focal_l2(v0.z) + focal_l2(v0.w));
            acc1 += (focal_l2(v1.x) + focal_l2(v1.y)) + (focal_l2(v1.z) + focal_l2(v1.w));
        }
        float fl = (acc0 + acc1) * (0.25f * LN2);

        __shared__ float rfl[4];
#pragma unroll
        for (int off = 32; off > 0; off >>= 1)
            fl += __shfl_down(fl, off);
        if (lane == 0) rfl[wave] = fl;
        __syncthreads();
        if (tid == 0)
            fl_part[b * NBLK + bx] = rfl[0] + rfl[1] + rfl[2] + rfl[3];
        return;
    }

    // ================= MATCH (VALU-bound) =================
    const int a0 = bx * ABLK;

    __shared__ float4 tbox[T_CNT];
    __shared__ float  taT[T_CNT];      // target area + 1e-8 folded
    __shared__ int    tcl[T_CNT];
    __shared__ int    wcnt[4];
    __shared__ int    excl_idx[ABLK];
    __shared__ float  rv[4][4];

    if (tid < T_CNT) {
        float4 bt = reinterpret_cast<const float4*>(bbox_tgts)[b * T_CNT + tid];
        // tlbr -> cthw -> tlbr (reference roundtrip)
        float cx = (bt.x + bt.z) * 0.5f;
        float cy = (bt.y + bt.w) * 0.5f;
        float sx = bt.z - bt.x;
        float sy = bt.w - bt.y;
        float4 tb;
        tb.x = cx - sx * 0.5f;
        tb.y = cy - sy * 0.5f;
        tb.z = cx + sx * 0.5f;
        tb.w = cy + sy * 0.5f;
        tbox[tid] = tb;
        taT[tid]  = (tb.z - tb.x) * (tb.w - tb.y) + 1e-8f;
        tcl[tid]  = clas_tgts[b * T_CNT + tid];
    }
    __syncthreads();

    const int a = a0 + tid;
    float4 anc = reinterpret_cast<const float4*>(anchors)[a];
    const float ax1 = anc.x - anc.z * 0.5f;
    const float ay1 = anc.y - anc.w * 0.5f;
    const float ax2 = anc.x + anc.z * 0.5f;
    const float ay2 = anc.y + anc.w * 0.5f;
    const float areaA = anc.z * anc.w;

    float bn = -1.0f, bd = 1.0f;
    int   bj = 0;
#pragma unroll 8
    for (int j = 0; j < T_CNT; ++j) {
        float4 tb = tbox[j];                 // wave-uniform b128 broadcast
        float ix1 = fmaxf(ax1, tb.x);
        float iy1 = fmaxf(ay1, tb.y);
        float ix2 = fminf(ax2, tb.z);
        float iy2 = fminf(ay2, tb.w);
        float w = fmaxf(ix2 - ix1, 0.0f);
        float h = fmaxf(iy2 - iy1, 0.0f);
        float inter = w * h;
        float den = (areaA + taT[j]) - inter;
        if (inter * bd > bn * den) { bn = inter; bd = den; bj = j; }  // first-max
    }

    const f32x4* cp4b = reinterpret_cast<const f32x4*>(clas_preds)
                      + ((size_t)b * A_CNT + a0) * (C_CNT / 4);

    float bb   = 0.0f;
    float flc  = 0.0f;   // hot correction (scaled)
    float craw = 0.0f;   // raw excl-anchor focal_l2 sum (scaled later)
    float mloc = 0.0f;
    bool  excl = false;

    if (bn > 0.5f * bd) {                    // iou > MATCH_THR
        mloc = 1.0f;
        int code = tcl[bj] - 1;              // hot class in [0,79]
        float4 tb = tbox[bj];
        float gx = (tb.x + tb.z) * 0.5f;
        float gy = (tb.y + tb.w) * 0.5f;
        float gw = tb.z - tb.x;
        float gh = tb.w - tb.y;
        float4 bp = reinterpret_cast<const float4*>(bbox_preds)[(size_t)b * A_CNT + a];
        float t0 = ((gx - anc.x) / anc.z) * 10.0f;       // / SCALE 0.1
        float t1 = ((gy - anc.y) / anc.w) * 10.0f;
        float t2 = __logf(gw / anc.z + 1e-8f) * 5.0f;    // / SCALE 0.2
        float t3 = __logf(gh / anc.w + 1e-8f) * 5.0f;
        float d, ad;
        d = bp.x - t0; ad = fabsf(d); bb += (ad < 1.0f) ? 0.5f * d * d : ad - 0.5f;
        d = bp.y - t1; ad = fabsf(d); bb += (ad < 1.0f) ? 0.5f * d * d : ad - 0.5f;
        d = bp.z - t2; ad = fabsf(d); bb += (ad < 1.0f) ? 0.5f * d * d : ad - 0.5f;
        d = bp.w - t3; ad = fabsf(d); bb += (ad < 1.0f) ? 0.5f * d * d : ad - 0.5f;

        // hot focal correction, same log2-form as the streamer for tight cancel
        float x  = clas_preds[((size_t)b * A_CNT + a) * C_CNT + code];
        float e  = __builtin_amdgcn_exp2f(x * RLN2);
        float t  = 1.0f + e;
        float inv = __builtin_amdgcn_rcpf(t);
        float ps = e * inv;
        float q  = 1.0f - ps;
        float L  = __builtin_amdgcn_logf(t);
        float sp = LN2 * L;                              // softplus(x)
        flc = 0.75f * q * q * (sp - x) - 0.25f * ps * ps * sp;
    } else {
        excl = (bn >= 0.4f * bd);            // 0.4 <= iou <= 0.5: excluded
    }

    // ---- compact excluded anchors (deterministic ballot order) ----
    unsigned long long bm = __ballot(excl);
    if (lane == 0) wcnt[wave] = __popcll(bm);
    __syncthreads();
    int wbase = 0;
#pragma unroll
    for (int w = 0; w < 4; ++w) wbase += (w < wave) ? wcnt[w] : 0;
    const int E = wcnt[0] + wcnt[1] + wcnt[2] + wcnt[3];
    if (excl) {
        int rank = wbase + __popcll(bm & ((1ull << lane) - 1ull));
        excl_idx[rank] = tid;
    }
    __syncthreads();

    // ---- subtract excluded anchors' unmasked focal (20 threads/anchor) ----
    for (int base = 0; base < E; base += 12) {
        int idx  = base + tid / 20;
        int part = tid % 20;
        if (tid < 240 && idx < E) {
            int al = excl_idx[idx];
            f32x4 v = cp4b[(size_t)al * 20 + part];
            craw -= (focal_l2(v.x) + focal_l2(v.y)) + (focal_l2(v.z) + focal_l2(v.w));
        }
    }

    // ---- block reduction of {bb, flc+scaled craw, m} ----
    flc = fmaf(0.25f * LN2, craw, flc);
#pragma unroll
    for (int off = 32; off > 0; off >>= 1) {
        bb   += __shfl_down(bb, off);
        flc  += __shfl_down(flc, off);
        mloc += __shfl_down(mloc, off);
    }
    if (lane == 0) { rv[wave][0] = bb; rv[wave][1] = flc; rv[wave][2] = mloc; }
    __syncthreads();
    if (tid == 0) {
        int slot = b * NBLK + bx;
        bb_part[slot]  = rv[0][0] + rv[1][0] + rv[2][0] + rv[3][0];
        flc_part[slot] = rv[0][1] + rv[1][1] + rv[2][1] + rv[3][1];
        m_part[slot]   = rv[0][2] + rv[1][2] + rv[2][2] + rv[3][2];
    }
}

// ---------- Finalize (coalesced -> LDS -> per-wave reduce) ----------
__global__ __launch_bounds__(256) void rnfl_final(
    const float* __restrict__ bb_part,
    const float* __restrict__ fl_part,
    const float* __restrict__ flc_part,
    const float* __restrict__ m_part,
    float* __restrict__ out)
{
    __shared__ float bbL[NSLOT], flL[NSLOT], fcL[NSLOT], mL[NSLOT];  // 48 KB
    __shared__ float wacc[4];
    const int tid = threadIdx.x, lane = tid & 63, wave = tid >> 6;

#pragma unroll
    for (int k = 0; k < NSLOT / 256; ++k) {   // 12 coalesced loads per array
        int s = k * 256 + tid;
        bbL[s] = bb_part[s];
        flL[s] = fl_part[s];
        fcL[s] = flc_part[s];
        mL[s]  = m_part[s];
    }
    __syncthreads();

    float lacc = 0.0f;
    for (int img = wave; img < B_CNT; img += 4) {
        float bb = 0.0f, fl = 0.0f, m = 0.0f;
#pragma unroll
        for (int s = 0; s < 3; ++s) {         // 3*64 = 192 = NBLK
            int i = img * NBLK + s * 64 + lane;
            bb += bbL[i];
            fl += flL[i] + fcL[i];
            m  += mL[i];
        }
#pragma unroll
        for (int off = 32; off > 0; off >>= 1) {
            bb += __shfl_down(bb, off);
            fl += __shfl_down(fl, off);
            m  += __shfl_down(m, off);
        }
        if (lane == 0)
            lacc += bb / fmaxf(m * 4.0f, 1.0f) + fl / fmaxf(m, 1.0f);
    }
    if (lane == 0) wacc[wave] = lacc;
    __syncthreads();
    if (tid == 0)
        out[0] = (wacc[0] + wacc[1] + wacc[2] + wacc[3]) / (float)B_CNT;
}

extern "C" void kernel_launch(void* const* d_in, const int* in_sizes, int n_in,
                              void* d_out, int out_size, void* d_ws, size_t ws_size,
                              hipStream_t stream)
{
    const float* clas_preds = (const float*)d_in[0];
    const float* bbox_preds = (const float*)d_in[1];
    const float* bbox_tgts  = (const float*)d_in[2];
    const int*   clas_tgts  = (const int*)d_in[3];
    const float* anchors    = (const float*)d_in[4];
    float* out = (float*)d_out;

    float* bb_part  = (float*)d_ws;
    float* fl_part  = bb_part  + NSLOT;
    float* flc_part = fl_part  + NSLOT;
    float* m_part   = flc_part + NSLOT;

    rnfl_main<<<2 * NSLOT, ABLK, 0, stream>>>(clas_preds, bbox_preds, bbox_tgts,
                                              clas_tgts, anchors,
                                              bb_part, fl_part, flc_part, m_part);
    rnfl_final<<<1, 256, 0, stream>>>(bb_part, fl_part, flc_part, m_part, out);
}